// Round 2
// baseline (856.619 us; speedup 1.0000x reference)
//
#include <hip/hip_runtime.h>
#include <hip/hip_bf16.h>
#include <stdint.h>

// Problem constants: B=4, L=2048, D=512, H=8, dh=64, BH=32.
// Faithful-quirk mapping: head h of batch b = rows [h*2048,(h+1)*2048) of the
// flat (B, L*D) projection buffer viewed as (B, 16384, 64).

typedef __attribute__((ext_vector_type(4))) float f32x4;
typedef __attribute__((ext_vector_type(8))) short bf16x8;

__device__ __forceinline__ ushort f2b(float x) {
  uint u = __builtin_bit_cast(uint, x);
  uint r = u + 0x7fffu + ((u >> 16) & 1u);   // RNE
  return (ushort)(r >> 16);
}

// ---------------- fp32 -> bf16 convert (vectorized) ----------------
__global__ void k_f2b(const float* __restrict__ s, ushort* __restrict__ d) {
  int i = (blockIdx.x * 256 + threadIdx.x) * 4;
  float4 v = *(const float4*)&s[i];
  ushort4 o;
  o.x = f2b(v.x); o.y = f2b(v.y); o.z = f2b(v.z); o.w = f2b(v.w);
  *(ushort4*)&d[i] = o;
}

// ---------------- weight transpose + convert: W[k][n] -> WT[n][k] bf16 ----
__global__ void k_wtrans(const float* __restrict__ W, ushort* __restrict__ WT) {
  __shared__ ushort tl[64][72];
  const int c0 = blockIdx.x * 64, r0 = blockIdx.y * 64;
  const int t = threadIdx.x;
  const int col = t & 63, rr = t >> 6;
#pragma unroll
  for (int p = 0; p < 16; ++p) {
    int row = rr + p * 4;
    tl[col][row] = f2b(W[(size_t)(r0 + row) * 512 + c0 + col]);
  }
  __syncthreads();
#pragma unroll
  for (int p = 0; p < 16; ++p) {
    int orow = rr + p * 4;
    WT[(size_t)(c0 + orow) * 512 + r0 + col] = tl[orow][col];
  }
}

// ---------------- mask pack: bitsT[b][j][i/32] (bit = i%32) ---------------
__global__ void k_pack(const int* __restrict__ mask, uint* __restrict__ bits) {
  const int t = threadIdx.x;
  const int lj = t & 63, lw = t >> 6;              // 64 j x 4 words per block
  const int b = blockIdx.x >> 9;
  const int rem = blockIdx.x & 511;
  const int jb = rem >> 4, wb = rem & 15;
  const int j = jb * 64 + lj;
  const int w = wb * 4 + lw;
  uint acc = 0;
#pragma unroll
  for (int ii = 0; ii < 32; ++ii) {
    int i = w * 32 + ii;
    int m = mask[(size_t)(b * 2048 + i) * 2048 + j];   // coalesced across lanes
    acc |= (m != 0 ? 1u : 0u) << ii;
  }
  bits[(size_t)(b * 2048 + j) * 64 + w] = acc;
}

// ---------------- V transpose per head: Pv[bh][j][d] -> vT[bh][d][j] ------
__global__ void k_transv(const ushort* __restrict__ Pv, ushort* __restrict__ vT) {
  __shared__ ushort tl[64][72];
  const int bh = blockIdx.x, j0 = blockIdx.y * 64;
  const int t = threadIdx.x;
  const ushort* src = Pv + ((size_t)bh * 2048 + j0) * 64;
#pragma unroll
  for (int p = 0; p < 16; ++p) {
    int e = t + p * 256;
    int j = e >> 6, d = e & 63;
    tl[d][j] = src[j * 64 + d];
  }
  __syncthreads();
  ushort* dst = vT + (size_t)bh * 131072 + j0;
#pragma unroll
  for (int p = 0; p < 16; ++p) {
    int e = t + p * 256;
    int d = e >> 6, j = e & 63;
    dst[(size_t)d * 2048 + j] = tl[d][j];
  }
}

// ---------------- GEMM (B^T form): C[M=8192][512] = A @ BT^T + bias -------
// FOUT=0: bf16 out with scale; FOUT=1: fp32 out.
template <int FOUT>
__global__ __launch_bounds__(256, 2) void k_gemm_bt(
    const ushort* __restrict__ A, const ushort* __restrict__ BT,
    const float* __restrict__ bias, float scale,
    ushort* __restrict__ Cb, float* __restrict__ Cf) {
  __shared__ __align__(16) ushort As[128 * 40];
  __shared__ __align__(16) ushort Bs[128 * 40];
  const int t = threadIdx.x;
  const int wave = t >> 6, lane = t & 63, quad = lane >> 4, l16 = lane & 15;
  const int wm = wave & 1, wn = wave >> 1;
  const int m0 = blockIdx.x * 128, n0 = blockIdx.y * 128;
  f32x4 acc[4][4];
#pragma unroll
  for (int a = 0; a < 4; ++a)
#pragma unroll
    for (int b = 0; b < 4; ++b) acc[a][b] = f32x4{0.f, 0.f, 0.f, 0.f};
  const int srow = t >> 2, scol = (t & 3) * 8;
  for (int k0 = 0; k0 < 512; k0 += 32) {
    __syncthreads();
#pragma unroll
    for (int c = 0; c < 2; ++c) {
      int row = srow + c * 64;
      uint4 va = *(const uint4*)&A[(size_t)(m0 + row) * 512 + k0 + scol];
      *(uint4*)&As[row * 40 + scol] = va;
      uint4 vb = *(const uint4*)&BT[(size_t)(n0 + row) * 512 + k0 + scol];
      *(uint4*)&Bs[row * 40 + scol] = vb;
    }
    __syncthreads();
    bf16x8 af[4], bfr[4];
#pragma unroll
    for (int mt = 0; mt < 4; ++mt)
      af[mt] = *(const bf16x8*)&As[(wm * 64 + mt * 16 + l16) * 40 + quad * 8];
#pragma unroll
    for (int nt = 0; nt < 4; ++nt)
      bfr[nt] = *(const bf16x8*)&Bs[(wn * 64 + nt * 16 + l16) * 40 + quad * 8];
#pragma unroll
    for (int mt = 0; mt < 4; ++mt)
#pragma unroll
      for (int nt = 0; nt < 4; ++nt)
        acc[mt][nt] = __builtin_amdgcn_mfma_f32_16x16x32_bf16(af[mt], bfr[nt],
                                                              acc[mt][nt], 0, 0, 0);
  }
#pragma unroll
  for (int mt = 0; mt < 4; ++mt)
#pragma unroll
    for (int nt = 0; nt < 4; ++nt) {
      const int gr = m0 + wm * 64 + mt * 16 + quad * 4;
      const int gc = n0 + wn * 64 + nt * 16 + l16;
      const float bv = bias[gc];
#pragma unroll
      for (int r = 0; r < 4; ++r) {
        float x = (acc[mt][nt][r] + bv) * scale;
        if (FOUT)
          Cf[(size_t)(gr + r) * 512 + gc] = x;
        else
          Cb[(size_t)(gr + r) * 512 + gc] = f2b(x);
      }
    }
}

// ---------------- fused attention: 2-phase softmax + PV -------------------
// grid (32 bh, 16 q-tiles), 256 threads = 4 waves, waves 2x2 over (q, j).
__global__ __launch_bounds__(256, 2) void k_attn(
    const ushort* __restrict__ Pq, const ushort* __restrict__ Pk,
    const ushort* __restrict__ vT, const uint* __restrict__ mbits,
    float* __restrict__ Pout, ushort* __restrict__ attn_b) {
  __shared__ __align__(16) char smem_raw[4 * 4608 * 2];  // 36864 B
  __shared__ float lds_rs[128];
  ushort* p_l = (ushort*)smem_raw;          // per-wave 64x72 bf16 tiles
  float* attn_l = (float*)smem_raw;         // reused after phase 2: 128x64 f32

  const int bh = blockIdx.x;
  const int b = bh >> 3;
  const int q0 = blockIdx.y * 128;
  const int t = threadIdx.x;
  const int wave = t >> 6, lane = t & 63;
  const int quad = lane >> 4, l16 = lane & 15;
  const int wq = wave & 1, jw = wave >> 1;
  const int qbase = q0 + wq * 64;

  // preload q A-fragments (q pre-scaled by 1/32 at projection time)
  const ushort* qptr = Pq + ((size_t)(bh * 2048 + qbase)) * 64;
  bf16x8 qf[4][2];
#pragma unroll
  for (int mt = 0; mt < 4; ++mt)
#pragma unroll
    for (int s = 0; s < 2; ++s)
      qf[mt][s] = *(const bf16x8*)&qptr[(mt * 16 + l16) * 64 + s * 32 + quad * 8];

  const ushort* kbase = Pk + (size_t)bh * 2048 * 64;
  const uint* mb = mbits + (size_t)b * 2048 * 64;
  const int wword = qbase >> 5;

  if (t < 128) lds_rs[t] = 0.f;
  __syncthreads();

  // ---------------- phase 1: row sums of exp(s)*mask ----------------
  float rs[16];
#pragma unroll
  for (int r = 0; r < 16; ++r) rs[r] = 0.f;

  for (int it = 0; it < 16; ++it) {
    const int j0 = it * 128 + jw * 64;
    bf16x8 kf[4][2];
    uint wlo[4], whi[4];
#pragma unroll
    for (int nt = 0; nt < 4; ++nt) {
      const int c = j0 + nt * 16 + l16;
#pragma unroll
      for (int s = 0; s < 2; ++s)
        kf[nt][s] = *(const bf16x8*)&kbase[(size_t)c * 64 + s * 32 + quad * 8];
      wlo[nt] = mb[c * 64 + wword];
      whi[nt] = mb[c * 64 + wword + 1];
    }
#pragma unroll
    for (int mt = 0; mt < 4; ++mt)
#pragma unroll
      for (int nt = 0; nt < 4; ++nt) {
        f32x4 acc = f32x4{0.f, 0.f, 0.f, 0.f};
        acc = __builtin_amdgcn_mfma_f32_16x16x32_bf16(qf[mt][0], kf[nt][0], acc, 0, 0, 0);
        acc = __builtin_amdgcn_mfma_f32_16x16x32_bf16(qf[mt][1], kf[nt][1], acc, 0, 0, 0);
        const uint wsel = (mt & 2) ? whi[nt] : wlo[nt];
        const int bitb = (mt & 1) * 16 + quad * 4;
#pragma unroll
        for (int r = 0; r < 4; ++r) {
          float e = ((wsel >> (bitb + r)) & 1u) ? __expf(acc[r]) : 0.f;
          rs[mt * 4 + r] += e;
        }
      }
  }
  // reduce across the 16 lanes that share each row
#pragma unroll
  for (int r = 0; r < 16; ++r)
#pragma unroll
    for (int off = 1; off < 16; off <<= 1) rs[r] += __shfl_xor(rs[r], off, 64);
  if (l16 == 0) {
#pragma unroll
    for (int mt = 0; mt < 4; ++mt)
#pragma unroll
      for (int r = 0; r < 4; ++r)
        atomicAdd(&lds_rs[wq * 64 + mt * 16 + quad * 4 + r], rs[mt * 4 + r]);
  }
  __syncthreads();
  if (t < 128) lds_rs[t] = 1.0f / lds_rs[t];
  __syncthreads();
  float inv[16];
#pragma unroll
  for (int mt = 0; mt < 4; ++mt)
#pragma unroll
    for (int r = 0; r < 4; ++r)
      inv[mt * 4 + r] = lds_rs[wq * 64 + mt * 16 + quad * 4 + r];

  // ---------------- phase 2: p = exp*mask*inv, store p, accumulate PV -----
  f32x4 pv[4][4];
#pragma unroll
  for (int a = 0; a < 4; ++a)
#pragma unroll
    for (int c = 0; c < 4; ++c) pv[a][c] = f32x4{0.f, 0.f, 0.f, 0.f};

  float* pout = Pout + ((size_t)(bh * 2048 + qbase)) * 2048;
  const ushort* vTb = vT + (size_t)bh * 131072;
  ushort* pw = p_l + wave * 4608;

  for (int it = 0; it < 16; ++it) {
    const int j0 = it * 128 + jw * 64;
    bf16x8 kf[4][2];
    uint wlo[4], whi[4];
#pragma unroll
    for (int nt = 0; nt < 4; ++nt) {
      const int c = j0 + nt * 16 + l16;
#pragma unroll
      for (int s = 0; s < 2; ++s)
        kf[nt][s] = *(const bf16x8*)&kbase[(size_t)c * 64 + s * 32 + quad * 8];
      wlo[nt] = mb[c * 64 + wword];
      whi[nt] = mb[c * 64 + wword + 1];
    }
#pragma unroll
    for (int mt = 0; mt < 4; ++mt)
#pragma unroll
      for (int nt = 0; nt < 4; ++nt) {
        f32x4 acc = f32x4{0.f, 0.f, 0.f, 0.f};
        acc = __builtin_amdgcn_mfma_f32_16x16x32_bf16(qf[mt][0], kf[nt][0], acc, 0, 0, 0);
        acc = __builtin_amdgcn_mfma_f32_16x16x32_bf16(qf[mt][1], kf[nt][1], acc, 0, 0, 0);
        const uint wsel = (mt & 2) ? whi[nt] : wlo[nt];
        const int bitb = (mt & 1) * 16 + quad * 4;
#pragma unroll
        for (int r = 0; r < 4; ++r) {
          float p = ((wsel >> (bitb + r)) & 1u) ? __expf(acc[r]) * inv[mt * 4 + r] : 0.f;
          pout[(size_t)(mt * 16 + quad * 4 + r) * 2048 + j0 + nt * 16 + l16] = p;
          pw[(mt * 16 + quad * 4 + r) * 72 + nt * 16 + l16] = f2b(p);
        }
      }
    __syncthreads();
#pragma unroll
    for (int s = 0; s < 2; ++s) {
      bf16x8 af[4], vf[4];
#pragma unroll
      for (int mt = 0; mt < 4; ++mt)
        af[mt] = *(const bf16x8*)&pw[(mt * 16 + l16) * 72 + s * 32 + quad * 8];
#pragma unroll
      for (int nt = 0; nt < 4; ++nt)
        vf[nt] = *(const bf16x8*)&vTb[(size_t)(nt * 16 + l16) * 2048 + j0 + s * 32 + quad * 8];
#pragma unroll
      for (int mt = 0; mt < 4; ++mt)
#pragma unroll
        for (int nt = 0; nt < 4; ++nt)
          pv[mt][nt] = __builtin_amdgcn_mfma_f32_16x16x32_bf16(af[mt], vf[nt],
                                                               pv[mt][nt], 0, 0, 0);
    }
    __syncthreads();
  }

  // merge the two j-halves and emit attn (bf16) for the output projection
  if (jw == 0) {
#pragma unroll
    for (int mt = 0; mt < 4; ++mt)
#pragma unroll
      for (int nt = 0; nt < 4; ++nt)
#pragma unroll
        for (int r = 0; r < 4; ++r)
          attn_l[(wq * 64 + mt * 16 + quad * 4 + r) * 64 + nt * 16 + l16] = pv[mt][nt][r];
  }
  __syncthreads();
  if (jw == 1) {
#pragma unroll
    for (int mt = 0; mt < 4; ++mt)
#pragma unroll
      for (int nt = 0; nt < 4; ++nt)
#pragma unroll
        for (int r = 0; r < 4; ++r) {
          int rl = wq * 64 + mt * 16 + quad * 4 + r;
          int cl = nt * 16 + l16;
          float v2 = pv[mt][nt][r] + attn_l[rl * 64 + cl];
          attn_b[(size_t)(bh * 2048 + q0 + rl) * 64 + cl] = f2b(v2);
        }
  }
}

extern "C" void kernel_launch(void* const* d_in, const int* in_sizes, int n_in,
                              void* d_out, int out_size, void* d_ws, size_t ws_size,
                              hipStream_t stream) {
  const float* Q = (const float*)d_in[0];
  const float* K = (const float*)d_in[1];
  const float* V = (const float*)d_in[2];
  const int* mask = (const int*)d_in[3];
  const float* Wq = (const float*)d_in[4];
  const float* bq = (const float*)d_in[5];
  const float* Wk = (const float*)d_in[6];
  const float* bk = (const float*)d_in[7];
  const float* Wv = (const float*)d_in[8];
  const float* bv = (const float*)d_in[9];
  const float* Wo = (const float*)d_in[10];
  const float* bo = (const float*)d_in[11];

  float* out = (float*)d_out;
  float* pdist = out + 4194304;  // attn_dist region (512 MB)

  // Scratch inside the attn_dist region: dead BEFORE k_attn overwrites it.
  // (Nothing here may be read after k_attn launches!)
  char* db = (char*)d_out;
  ushort* Qb = (ushort*)(db + 16777216);
  ushort* Kb = Qb + 4194304;
  ushort* Vb = Kb + 4194304;
  ushort* Pv = Vb + 4194304;
  ushort* WqT = Pv + 4194304;
  ushort* WkT = WqT + 262144;
  ushort* WvT = WkT + 262144;

  // Buffers live across/after k_attn go in d_ws (34.5 MB total).
  char* wb = (char*)d_ws;
  ushort* Pq = (ushort*)wb;
  ushort* Pk = Pq + 4194304;
  ushort* vTw = Pk + 4194304;
  ushort* attn_b = vTw + 4194304;
  uint* mbits = (uint*)(attn_b + 4194304);
  ushort* WoT = (ushort*)(mbits + 524288);   // read AFTER k_attn — must not be
                                             // in the pdist region

  k_wtrans<<<dim3(8, 8), 256, 0, stream>>>(Wq, WqT);
  k_wtrans<<<dim3(8, 8), 256, 0, stream>>>(Wk, WkT);
  k_wtrans<<<dim3(8, 8), 256, 0, stream>>>(Wv, WvT);
  k_wtrans<<<dim3(8, 8), 256, 0, stream>>>(Wo, WoT);
  k_f2b<<<4096, 256, 0, stream>>>(Q, Qb);
  k_f2b<<<4096, 256, 0, stream>>>(K, Kb);
  k_f2b<<<4096, 256, 0, stream>>>(V, Vb);
  k_pack<<<2048, 256, 0, stream>>>(mask, mbits);
  // q carries the faithful 1/(dh/2) = 1/32 logit scale
  k_gemm_bt<0><<<dim3(64, 4), 256, 0, stream>>>(Qb, WqT, bq, 0.03125f, Pq, nullptr);
  k_gemm_bt<0><<<dim3(64, 4), 256, 0, stream>>>(Kb, WkT, bk, 1.0f, Pk, nullptr);
  k_gemm_bt<0><<<dim3(64, 4), 256, 0, stream>>>(Vb, WvT, bv, 1.0f, Pv, nullptr);
  k_transv<<<dim3(32, 32), 256, 0, stream>>>(Pv, vTw);
  k_attn<<<dim3(32, 16), 256, 0, stream>>>(Pq, Pk, vTw, mbits, pdist, attn_b);
  k_gemm_bt<1><<<dim3(64, 4), 256, 0, stream>>>(attn_b, WoT, bo, 1.0f, nullptr, out);
}